// Round 12
// baseline (1364.876 us; speedup 1.0000x reference)
//
#include <hip/hip_runtime.h>
#include <hip/hip_fp16.h>
#include <math.h>

#define TID threadIdx.x

typedef _Float16 h2vec __attribute__((ext_vector_type(2)));
typedef _Float16 f16x8 __attribute__((ext_vector_type(8)));
typedef float f32x4 __attribute__((ext_vector_type(4)));
typedef float f32x2v __attribute__((ext_vector_type(2)));

#if __has_builtin(__builtin_elementwise_fma)
#define EFMA(a, b, c) __builtin_elementwise_fma((a), (b), (c))
#else
static __device__ __forceinline__ f32x2v EFMA(f32x2v a, f32x2v b, f32x2v c) {
    f32x2v r;
    r.x = fmaf(a.x, b.x, c.x);
    r.y = fmaf(a.y, b.y, c.y);
    return r;
}
#endif

// fp16 pair dot into fp32 accumulator: v_dot2_f32_f16
static __device__ __forceinline__ float fdot2(unsigned a, unsigned b, float c) {
    h2vec av, bv;
    __builtin_memcpy(&av, &a, 4);
    __builtin_memcpy(&bv, &b, 4);
    return __builtin_amdgcn_fdot2(av, bv, c, false);
}

static __device__ __forceinline__ unsigned packh2(float a, float b) {
    __half2 hh = __floats2half2_rn(a, b);
    unsigned u;
    __builtin_memcpy(&u, &hh, 4);
    return u;
}

// Monotone float<->uint encoding for integer atomicMax on floats.
static __device__ __forceinline__ unsigned encf(float f) {
    unsigned u = __float_as_uint(f);
    return (u >> 31) ? ~u : (u | 0x80000000u);
}
static __device__ __forceinline__ float decf(unsigned e) {
    unsigned u = (e >> 31) ? (e & 0x7fffffffu) : ~e;
    return __uint_as_float(u);
}

// Wave-uniform sum via DPP ladder; only lane63 true total, readlane broadcasts.
static __device__ __forceinline__ int wave_sum(int v) {
    v += __builtin_amdgcn_update_dpp(0, v, 0x111, 0xf, 0xf, true);  // row_shr:1
    v += __builtin_amdgcn_update_dpp(0, v, 0x112, 0xf, 0xf, true);  // row_shr:2
    v += __builtin_amdgcn_update_dpp(0, v, 0x114, 0xf, 0xf, true);  // row_shr:4
    v += __builtin_amdgcn_update_dpp(0, v, 0x118, 0xf, 0xf, true);  // row_shr:8
    v += __builtin_amdgcn_update_dpp(0, v, 0x142, 0xf, 0xf, true);  // row_bcast15
    v += __builtin_amdgcn_update_dpp(0, v, 0x143, 0xf, 0xf, true);  // row_bcast31
    return __builtin_amdgcn_readlane(v, 63);
}

// u64 max with partner brought in by DPP; bound_ctrl=true shifts in 0 (identity).
template <int CTRL>
static __device__ __forceinline__ unsigned long long dpp_max_u64(unsigned long long k) {
    int lo = (int)(unsigned)(k & 0xffffffffULL);
    int hi = (int)(unsigned)(k >> 32);
    int lo2 = __builtin_amdgcn_update_dpp(0, lo, CTRL, 0xf, 0xf, true);
    int hi2 = __builtin_amdgcn_update_dpp(0, hi, CTRL, 0xf, 0xf, true);
    unsigned long long k2 = ((unsigned long long)(unsigned)hi2 << 32) | (unsigned)lo2;
    return k2 > k ? k2 : k;
}

// ---------------------------------------------------------------------------
// fp32 -> fp16 B-fragment pack for mfma_f32_16x16x32_f16 (one slot per t).
// ---------------------------------------------------------------------------
static __device__ __forceinline__ void pack_slot(const float* __restrict__ W,
                                                 unsigned* __restrict__ out,
                                                 int K, int ncols, int t) {
    int lane = t & 63;
    int frag = t >> 6;
    int nct = ncols >> 4;
    int ks = frag / nct, ct = frag - ks * nct;
    int kbase = (ks << 5) + ((lane >> 4) << 3);
    int cc = (ct << 4) + (lane & 15);
    unsigned o[4];
#pragma unroll
    for (int i = 0; i < 4; ++i) {
        int k0 = kbase + 2 * i, k1 = kbase + 2 * i + 1;
        float f0 = (k0 < K) ? W[(size_t)k0 * ncols + cc] : 0.f;
        float f1 = (k1 < K) ? W[(size_t)k1 * ncols + cc] : 0.f;
        o[i] = packh2(f0, f1);
    }
    *(uint4*)&out[(size_t)t * 4] = make_uint4(o[0], o[1], o[2], o[3]);
}

// ---------------------------------------------------------------------------
// Merged pack + curvature kernel. Blocks 0-389 pack the 6 weight matrices
// (block 0 also inits gfeat encodings); blocks 390-453 compute curvature.
// ---------------------------------------------------------------------------
__global__ __launch_bounds__(256) void pack_curv_kernel(
    const float* __restrict__ Wc, const float* __restrict__ Wa,
    const float* __restrict__ Wb, const float* __restrict__ W3a,
    const float* __restrict__ W3b, const float* __restrict__ W3c,
    unsigned* __restrict__ WcH, unsigned* __restrict__ WaH,
    unsigned* __restrict__ WbH, unsigned* __restrict__ W3aH,
    unsigned* __restrict__ W3bH, unsigned* __restrict__ W3cH,
    unsigned* __restrict__ gfeatE,
    const float* __restrict__ pos, float* __restrict__ curv) {
    __shared__ float4 sp[2048];
    int b = blockIdx.x;
    if (b < 390) {
        if (b == 0)
            for (int i = TID; i < 8192; i += 256) gfeatE[i] = 0u;  // enc identity
        if (b < 16)        pack_slot(Wc,  WcH,  128, 256,  b * 256 + TID);
        else if (b < 26)   pack_slot(Wa,  WaH,  131, 128,  (b - 16) * 256 + TID);
        else if (b < 34)   pack_slot(Wb,  WbH,  128, 128,  (b - 26) * 256 + TID);
        else if (b < 70)   pack_slot(W3a, W3aH, 259, 256,  (b - 34) * 256 + TID);
        else if (b < 134)  pack_slot(W3b, W3bH, 256, 512,  (b - 70) * 256 + TID);
        else               pack_slot(W3c, W3cH, 512, 1024, (b - 134) * 256 + TID);
        return;
    }
    int cb = b - 390;
    int cloud = cb >> 3;
    int base = cloud << 11;
    for (int j = TID; j < 2048; j += 256) {
        const float* p = pos + (size_t)(base + j) * 3;
        float x = p[0], y = p[1], z = p[2];
        sp[j] = make_float4(x, y, z, fmaf(x, x, fmaf(y, y, z * z)));
    }
    __syncthreads();
    int li = ((cb & 7) << 8) + TID;
    float4 pi = sp[li];
    float bd[10];
    int bi[10];
#pragma unroll
    for (int t = 0; t < 10; ++t) { bd[t] = 3.0e38f; bi[t] = 0; }
    for (int j = 0; j < 2048; ++j) {
        float4 pj = sp[j];
        float dot = fmaf(pi.x, pj.x, fmaf(pi.y, pj.y, pi.z * pj.z));
        float d2 = pi.w + pj.w - 2.0f * dot;   // same form as reference _sqdist
        if (d2 < bd[9]) {
            bd[9] = d2; bi[9] = j;
#pragma unroll
            for (int t = 9; t > 0; --t) {
                if (bd[t] < bd[t - 1]) {
                    float td = bd[t]; bd[t] = bd[t - 1]; bd[t - 1] = td;
                    int ti = bi[t]; bi[t] = bi[t - 1]; bi[t - 1] = ti;
                }
            }
        }
    }
    double sx = 0, sy = 0, sz = 0;
#pragma unroll
    for (int t = 0; t < 10; ++t) { float4 p = sp[bi[t]]; sx += p.x; sy += p.y; sz += p.z; }
    double mx = sx / 10.0, my = sy / 10.0, mz = sz / 10.0;
    double cxx = 0, cxy = 0, cxz = 0, cyy = 0, cyz = 0, czz = 0;
#pragma unroll
    for (int t = 0; t < 10; ++t) {
        float4 p = sp[bi[t]];
        double dx = p.x - mx, dy = p.y - my, dz = p.z - mz;
        cxx += dx * dx; cxy += dx * dy; cxz += dx * dz;
        cyy += dy * dy; cyz += dy * dz; czz += dz * dz;
    }
    cxx /= 10.0; cxy /= 10.0; cxz /= 10.0; cyy /= 10.0; cyz /= 10.0; czz /= 10.0;
    double q = (cxx + cyy + czz) / 3.0;
    double b00 = cxx - q, b11 = cyy - q, b22 = czz - q;
    double p2 = b00 * b00 + b11 * b11 + b22 * b22 +
                2.0 * (cxy * cxy + cxz * cxz + cyz * cyz);
    double lmin;
    if (p2 <= 0.0) {
        lmin = q;
    } else {
        double p = sqrt(p2 / 6.0);
        double inv = 1.0 / p;
        double c00 = b00 * inv, c01 = cxy * inv, c02 = cxz * inv;
        double c11 = b11 * inv, c12 = cyz * inv, c22 = b22 * inv;
        double detB = c00 * (c11 * c22 - c12 * c12)
                    - c01 * (c01 * c22 - c12 * c02)
                    + c02 * (c01 * c12 - c11 * c02);
        double r = 0.5 * detB;
        r = fmin(1.0, fmax(-1.0, r));
        double phi = acos(r) / 3.0;
        lmin = q + 2.0 * p * cos(phi + 2.0943951023931953);  // smallest eigenvalue
    }
    double s3 = cxx + cyy + czz;
    curv[base + li] = (float)(lmin / (s3 + 1e-8));
}

// ---------------------------------------------------------------------------
// Weighted FPS body — round-9 proven structure (measured best): 4 waves,
// packed f32x2 update, u64 key tree per lane, u64 DPP max ladder, lane63
// posts 1 record/wave, single barrier, fold 4. Key=(score_bits<<32)|(2047-idx).
// ---------------------------------------------------------------------------
template <int N, int M, int SLOTS>
static __device__ void fps_body(
    const float* __restrict__ srcpos, int stride, const float* __restrict__ srccurv,
    int cloud, float4* __restrict__ outPos, float* __restrict__ outCurv,
    float* __restrict__ outA, int ldA,
    float4* sp, int* sidx, unsigned long long* rec /* [8] */) {
    constexpr int PAIRS = SLOTS / 2;
    const float* cp = srcpos + (size_t)cloud * N * stride;
    for (int j = TID; j < N; j += 256)
        sp[j] = make_float4(cp[j * stride], cp[j * stride + 1], cp[j * stride + 2], 0.f);
    if (TID == 0) sidx[0] = 0;
    __syncthreads();
    f32x2v px[PAIRS], py[PAIRS], pz[PAIRS], md[PAIRS], wvv[PAIRS];
#pragma unroll
    for (int s = 0; s < PAIRS; ++s) {
        int p0 = ((2 * s) << 8) + TID, p1 = ((2 * s + 1) << 8) + TID;
        float4 q0 = sp[p0], q1 = sp[p1];
        px[s].x = q0.x; px[s].y = q1.x;
        py[s].x = q0.y; py[s].y = q1.y;
        pz[s].x = q0.z; pz[s].y = q1.z;
        md[s].x = 3.0e38f; md[s].y = 3.0e38f;
        wvv[s].x = fmaf(10.0f, srccurv[cloud * N + p0], 1.0f);
        wvv[s].y = fmaf(10.0f, srccurv[cloud * N + p1], 1.0f);
    }
    int lane = TID & 63, w4 = TID >> 6;
    float4 c0 = sp[0];
    float cx = c0.x, cy = c0.y, cz = c0.z;
    for (int t = 1; t < M; ++t) {
        f32x2v cxv, cyv, czv;
        cxv.x = cx; cxv.y = cx; cyv.x = cy; cyv.y = cy; czv.x = cz; czv.y = cz;
        unsigned long long kk[PAIRS];
#pragma unroll
        for (int s = 0; s < PAIRS; ++s) {
            f32x2v dx = px[s] - cxv, dy = py[s] - cyv, dz = pz[s] - czv;
            f32x2v nd = EFMA(dx, dx, EFMA(dy, dy, dz * dz));
            f32x2v m2 = __builtin_elementwise_min(md[s], nd);
            md[s] = m2;
            f32x2v sc = m2 * wvv[s];
            // score >= 0 -> float bits monotone under unsigned compare
            unsigned long long k0 =
                ((unsigned long long)__float_as_uint(sc.x) << 32) |
                (unsigned)(2047 - (((2 * s) << 8) + TID));
            unsigned long long k1 =
                ((unsigned long long)__float_as_uint(sc.y) << 32) |
                (unsigned)(2047 - (((2 * s + 1) << 8) + TID));
            kk[s] = k0 > k1 ? k0 : k1;
        }
        unsigned long long k = kk[0];
#pragma unroll
        for (int s = 1; s < PAIRS; ++s) k = kk[s] > k ? kk[s] : k;
        k = dpp_max_u64<0x111>(k);   // row_shr:1
        k = dpp_max_u64<0x112>(k);   // row_shr:2
        k = dpp_max_u64<0x114>(k);   // row_shr:4
        k = dpp_max_u64<0x118>(k);   // row_shr:8
        k = dpp_max_u64<0x142>(k);   // row_bcast15
        k = dpp_max_u64<0x143>(k);   // row_bcast31 -> lane63 has wave max
        int pbase = (t & 1) << 2;
        if (lane == 63) rec[pbase | w4] = k;
        __syncthreads();
        unsigned long long k0 = rec[pbase + 0];
        unsigned long long k1 = rec[pbase + 1];
        unsigned long long k2 = rec[pbase + 2];
        unsigned long long k3 = rec[pbase + 3];
        unsigned long long ka = k0 > k1 ? k0 : k1;
        unsigned long long kb = k2 > k3 ? k2 : k3;
        unsigned long long km = ka > kb ? ka : kb;
        int nbix = 2047 - (int)(unsigned)(km & 0xffffffffULL);  // uniform winner
        if (TID == 0) sidx[t] = nbix;
        float4 cc = sp[nbix];        // uniform (broadcast) read
        cx = cc.x; cy = cc.y; cz = cc.z;
    }
    __syncthreads();
    for (int j = TID; j < M; j += 256) {
        int id = sidx[j];
        float4 qv = sp[id];
        outPos[cloud * M + j] = qv;
        if (outCurv) outCurv[cloud * M + j] = srccurv[cloud * N + id];
        if (outA) {
            float* a = outA + (size_t)(cloud * M + j) * ldA;
            a[256] = qv.x; a[257] = qv.y; a[258] = qv.z;
        }
    }
}

// Standalone fps1 (2048 -> 1024)
__global__ __launch_bounds__(256, 1) void fps1_kernel(
    const float* __restrict__ pos, const float* __restrict__ curv,
    float4* __restrict__ pos1, float* __restrict__ curv1) {
    __shared__ float4 sp[2048];
    __shared__ int sidx[1024];
    __shared__ unsigned long long rec[8];
    fps_body<2048, 1024, 8>(pos, 3, curv, blockIdx.x, pos1, curv1, nullptr, 0,
                            sp, sidx, rec);
}

// ---------------------------------------------------------------------------
// Exact top-64 (smallest d2, idx tie-break) selection within one wave.
// ---------------------------------------------------------------------------
static __device__ __forceinline__ int select_k64(const unsigned int* ck, const int* ci,
                                                 int c, int lane, int* cnt2, int* sel,
                                                 int* nbOut) {
    if (c <= 64) {
        *nbOut = c;
        return (lane < c) ? ci[lane] : 0;
    }
    unsigned int T = 0;  // becomes the 64th-smallest key
    for (int bit = 31; bit >= 0; --bit) {
        unsigned int mid = T | (1u << bit);
        int cl = 0;
        for (int q = lane; q < c; q += 64) cl += (ck[q] < mid) ? 1 : 0;
        if (wave_sum(cl) < 64) T = mid;
    }
    int cl = 0;
    for (int q = lane; q < c; q += 64) cl += (ck[q] < T) ? 1 : 0;
    int need = 64 - wave_sum(cl);
    int TI = 0;  // becomes the need-th smallest idx among keys == T
    for (int bit = 11; bit >= 0; --bit) {
        int mid = TI | (1 << bit);
        int ce = 0;
        for (int q = lane; q < c; q += 64) ce += (ck[q] == T && ci[q] < mid) ? 1 : 0;
        if (wave_sum(ce) < need) TI = mid;
    }
    for (int q = lane; q < c; q += 64) {
        unsigned int kq = ck[q];
        int iq = ci[q];
        if (kq < T || (kq == T && iq <= TI)) sel[atomicAdd(cnt2, 1)] = iq;
    }
    *nbOut = 64;
    return sel[lane];
}

// ---------------------------------------------------------------------------
// SA1 conv body (3->64->64->128). h2 staged to LDS as fp16 pairs; L3 is
// weights-stationary: lane = channel (wave-pair covers 128 ch), fdot2 inner.
// ---------------------------------------------------------------------------
union U1 {
    struct {
        float4 sp[2048];
        unsigned ck[4][256];
        int ci[4][256];
        int sel[4][64];
        int cnt[4], cnt2[4];
    } p;
    unsigned h2s[4][2048];   // [cent][n*32 + ((q*4) ^ ((n&7)*4)) + k], half2 elems
};

static __device__ void conv1_body(
    int bid, U1& u,
    const float* __restrict__ pos, const float4* __restrict__ pos1,
    const float* __restrict__ W1, const float* __restrict__ B1,
    const float* __restrict__ W2, const float* __restrict__ B2,
    const float* __restrict__ W3, const float* __restrict__ B3,
    float* __restrict__ x1) {
    __shared__ int nbs[4];
    int cloud = bid >> 8;
    int w4 = TID >> 6, lane = TID & 63;
    int centb = (bid & 255) << 2;
    int g = (cloud << 10) + centb + w4;
    int base = cloud << 11;
    for (int j = TID; j < 2048; j += 256) {
        const float* p = pos + (size_t)(base + j) * 3;
        u.p.sp[j] = make_float4(p[0], p[1], p[2], 0.f);
    }
    if (lane == 0) { u.p.cnt[w4] = 0; u.p.cnt2[w4] = 0; }
    __syncthreads();
    float4 cq = pos1[g];
    double cx = cq.x, cy = cq.y, cz = cq.z;
    for (int s = 0; s < 32; ++s) {
        int j = (s << 6) + lane;
        float4 pj = u.p.sp[j];
        double dx = (double)pj.x - cx, dy = (double)pj.y - cy, dz = (double)pj.z - cz;
        double d2 = dx * dx + dy * dy + dz * dz;
        if (d2 <= 0.2 * 0.2) {
            int p = atomicAdd(&u.p.cnt[w4], 1);
            if (p < 256) { u.p.ck[w4][p] = __float_as_uint((float)d2); u.p.ci[w4][p] = j; }
        }
    }
    __syncthreads();
    int c = min(u.p.cnt[w4], 256);
    int nb;
    int idxn = select_k64(u.p.ck[w4], u.p.ci[w4], c, lane, &u.p.cnt2[w4],
                          u.p.sel[w4], &nb);
    if (lane == 0) nbs[w4] = nb;
    float4 pn = u.p.sp[idxn];
    float rx = pn.x - cq.x, ry = pn.y - cq.y, rz = pn.z - cq.z;
    float h1[64];
#pragma unroll
    for (int cc2 = 0; cc2 < 64; ++cc2) {
        float v = fmaf(rx, W1[cc2], fmaf(ry, W1[64 + cc2], fmaf(rz, W1[128 + cc2], B1[cc2])));
        h1[cc2] = fmaxf(v, 0.f);
    }
    float h2[64];
#pragma unroll
    for (int cc2 = 0; cc2 < 64; ++cc2) h2[cc2] = B2[cc2];
#pragma unroll
    for (int i = 0; i < 64; ++i) {
        float hv = h1[i];
        const float* wr = W2 + i * 64;
#pragma unroll
        for (int cc2 = 0; cc2 < 64; ++cc2) h2[cc2] = fmaf(hv, wr[cc2], h2[cc2]);
    }
#pragma unroll
    for (int cc2 = 0; cc2 < 64; ++cc2) h2[cc2] = fmaxf(h2[cc2], 0.f);
    __syncthreads();   // all waves done with grouping buffers / sp
    {
        unsigned* hrow = &u.h2s[w4][lane << 5];
        int sw = (lane & 7) << 2;
#pragma unroll
        for (int q = 0; q < 8; ++q) {
            unsigned tmp[4];
#pragma unroll
            for (int k2 = 0; k2 < 4; ++k2) {
                int j = (q << 2) + k2;
                tmp[k2] = packh2(h2[2 * j], h2[2 * j + 1]);
            }
            *(uint4*)&hrow[(q << 2) ^ sw] = make_uint4(tmp[0], tmp[1], tmp[2], tmp[3]);
        }
    }
    __syncthreads();   // h2s + nbs visible block-wide
    // L3: lane = channel (wave pairs cover 128 ch), 2 centroids per lane
    int ch = ((w4 & 1) << 6) + lane;
    int cbase = (w4 >> 1) << 1;
    unsigned w2[32];
#pragma unroll
    for (int p = 0; p < 32; ++p)
        w2[p] = packh2(W3[(2 * p) * 128 + ch], W3[(2 * p + 1) * 128 + ch]);
    float bv = B3[ch];
#pragma unroll 1
    for (int ci2 = 0; ci2 < 2; ++ci2) {
        int cc = cbase + ci2;
        int nbc = nbs[cc];
        float m = -1e30f;
        for (int n = 0; n < nbc; ++n) {
            const unsigned* hr = &u.h2s[cc][n << 5];
            int sw2 = (n & 7) << 2;
            float a0 = 0.f, a1 = 0.f, a2 = 0.f, a3 = 0.f;
#pragma unroll
            for (int q = 0; q < 8; ++q) {
                uint4 hv = *(const uint4*)&hr[(q << 2) ^ sw2];
                a0 = fdot2(hv.x, w2[(q << 2) + 0], a0);
                a1 = fdot2(hv.y, w2[(q << 2) + 1], a1);
                a2 = fdot2(hv.z, w2[(q << 2) + 2], a2);
                a3 = fdot2(hv.w, w2[(q << 2) + 3], a3);
            }
            m = fmaxf(m, bv + (a0 + a1) + (a2 + a3));
        }
        x1[(size_t)((cloud << 10) + centb + cc) * 128 + ch] = m;
    }
}

// ---------------------------------------------------------------------------
// Merged launch: blocks 0-7 run fps2 (1024->256), blocks 8.. run conv1.
// ---------------------------------------------------------------------------
union UM {
    U1 c;
    struct {
        float4 sp[1024];
        unsigned long long rec[8];
        int sidx[256];
    } f;
};

__global__ __launch_bounds__(256, 2) void fps2_conv1_kernel(
    const float* __restrict__ pos, const float4* __restrict__ pos1,
    const float* __restrict__ curv1, float4* __restrict__ pos2,
    float* __restrict__ Abuf,
    const float* __restrict__ W1, const float* __restrict__ B1,
    const float* __restrict__ W2, const float* __restrict__ B2,
    const float* __restrict__ W3, const float* __restrict__ B3,
    float* __restrict__ x1) {
    __shared__ UM u;
    if (blockIdx.x < 8) {
        fps_body<1024, 256, 4>((const float*)pos1, 4, curv1, blockIdx.x, pos2,
                               nullptr, Abuf, 260, u.f.sp, u.f.sidx, u.f.rec);
    } else {
        conv1_body(blockIdx.x - 8, u.c, pos, pos1, W1, B1, W2, B2, W3, B3, x1);
    }
}

// ---------------------------------------------------------------------------
// SA2: radius r=0.4 grouping + PointNetConv(131->128->128->256) as MFMA GEMMs,
// restructured into a barrier-free per-wave row-chunk pipeline:
// per 16-row chunk: gather(fp16) -> L1 -> L2 -> transpose chunk -> L3 partial
// max. All LDS traffic is wave-local after the initial sp staging barrier.
// Per-wave region unions the dead grouping buffers. LDS 73 KB -> 2 blocks/CU.
// Layouts (stride-84 xs, stride-68 h1, chunk-XOR h2) identical to the
// verified round-7..11 kernel, just 16 rows at a time.
// ---------------------------------------------------------------------------
union WaveRegion {
    struct {
        unsigned ck[512];
        int ci[512];
        int sel[64];
        int cnt, cnt2;
    } g;
    struct {
        int idxl[64];
        unsigned relp[128];
        unsigned xs[1360];   // 16 rows x 84 dwords
        unsigned h1[1088];   // 16 rows x 68 dwords
        unsigned h2[1024];   // 16 rows x 64 dwords (chunk-XOR layout)
    } p;
};

__global__ __launch_bounds__(256, 2) void conv2_kernel(
    const float4* __restrict__ pos1, const float4* __restrict__ pos2,
    const float* __restrict__ x1,
    const unsigned* __restrict__ WaH, const float* __restrict__ Ba,
    const unsigned* __restrict__ WbH, const float* __restrict__ Bb,
    const unsigned* __restrict__ WcH, const float* __restrict__ Bc,
    float* __restrict__ Aout) {
    __shared__ float4 sp[1024];
    __shared__ WaveRegion wr[4];
    int cloud = blockIdx.x >> 6;
    int w4 = TID >> 6, lane = TID & 63;
    int centb = (blockIdx.x & 63) << 2;
    int g = (cloud << 8) + centb + w4;
    int quad = lane >> 4, l15 = lane & 15;
    for (int j = TID; j < 1024; j += 256) sp[j] = pos1[(cloud << 10) + j];
    if (lane == 0) { wr[w4].g.cnt = 0; wr[w4].g.cnt2 = 0; }
    __syncthreads();   // the ONLY block-wide barrier
    float4 cq = pos2[g];
    double cx = cq.x, cy = cq.y, cz = cq.z;
    for (int s = 0; s < 16; ++s) {
        int j = (s << 6) + lane;
        float4 pj = sp[j];
        double dx = (double)pj.x - cx, dy = (double)pj.y - cy, dz = (double)pj.z - cz;
        double d2 = dx * dx + dy * dy + dz * dz;
        if (d2 <= 0.4 * 0.4) {
            int p = atomicAdd(&wr[w4].g.cnt, 1);
            if (p < 512) { wr[w4].g.ck[p] = __float_as_uint((float)d2); wr[w4].g.ci[p] = j; }
        }
    }
    int c = min(wr[w4].g.cnt, 512);
    int nb;
    int idxn = select_k64(wr[w4].g.ck, wr[w4].g.ci, c, lane, &wr[w4].g.cnt2,
                          wr[w4].g.sel, &nb);
    float4 pn = sp[idxn];
    float rx = pn.x - cq.x, ry = pn.y - cq.y, rz = pn.z - cq.z;
    // switch own region to pipeline use (own grouping data dead)
    wr[w4].p.idxl[lane] = idxn;
    wr[w4].p.relp[2 * lane] = packh2(rx, ry);
    wr[w4].p.relp[2 * lane + 1] = packh2(rz, 0.f);
    float runM[16][4];
#pragma unroll
    for (int ct = 0; ct < 16; ++ct)
#pragma unroll
        for (int r = 0; r < 4; ++r) runM[ct][r] = -1e30f;
    int jrow = lane >> 2, part = lane & 3;
#pragma unroll 1
    for (int rt = 0; rt < 4; ++rt) {
        // --- gather chunk: 4 lanes per row, 32 consecutive x1 floats each ---
        {
            int grow = (rt << 4) + jrow;
            int srow = wr[w4].p.idxl[grow];
            const float4* src =
                (const float4*)(x1 + (size_t)((cloud << 10) + srow) * 128) + (part << 3);
            unsigned* xrow = &wr[w4].p.xs[jrow * 84];
#pragma unroll
            for (int q = 0; q < 4; ++q) {
                float4 a = src[2 * q], b = src[2 * q + 1];
                *(uint4*)&xrow[(part << 4) + (q << 2)] =
                    make_uint4(packh2(a.x, a.y), packh2(a.z, a.w),
                               packh2(b.x, b.y), packh2(b.z, b.w));
            }
            if (part == 3) {
                unsigned r0 = wr[w4].p.relp[2 * grow];
                unsigned r1 = wr[w4].p.relp[2 * grow + 1];
                *(uint4*)&xrow[64] = make_uint4(r0, r1, 0u, 0u);
                *(uint4*)&xrow[68] = make_uint4(0u, 0u, 0u, 0u);
                *(uint4*)&xrow[72] = make_uint4(0u, 0u, 0u, 0u);
                *(uint4*)&xrow[76] = make_uint4(0u, 0u, 0u, 0u);
                *(uint4*)&xrow[80] = make_uint4(0u, 0u, 0u, 0u);
            }
        }
        // --- L1: chunk h1 = xs[16x160] @ WaH ---
#pragma unroll 1
        for (int ct = 0; ct < 8; ++ct) {
            f16x8 bfrag[5];
#pragma unroll
            for (int ks = 0; ks < 5; ++ks) {
                uint4 bv = *(const uint4*)&WaH[(size_t)((((ks << 3) | ct) << 6) | lane) << 2];
                __builtin_memcpy(&bfrag[ks], &bv, 16);
            }
            f32x4 acc = {0.f, 0.f, 0.f, 0.f};
#pragma unroll
            for (int ks = 0; ks < 5; ++ks) {
                f16x8 af;
                uint4 av = *(const uint4*)&wr[w4].p.xs[l15 * 84 + (((ks << 2) + quad) << 2)];
                __builtin_memcpy(&af, &av, 16);
                acc = __builtin_amdgcn_mfma_f32_16x16x32_f16(af, bfrag[ks], acc, 0, 0, 0);
            }
            float bb = Ba[(ct << 4) + l15];
#pragma unroll
            for (int r = 0; r < 4; ++r) {
                float v = fmaxf(acc[r] + bb, 0.f);
                float vp = __shfl_xor(v, 1, 64);
                if (!(l15 & 1))
                    wr[w4].p.h1[((quad << 2) + r) * 68 + (ct << 3) + (l15 >> 1)] =
                        packh2(v, vp);
            }
        }
        // --- L2: chunk h2 = h1[16x128] @ WbH; write transpose chunk ---
#pragma unroll 1
        for (int ct = 0; ct < 8; ++ct) {
            f16x8 bfrag[4];
#pragma unroll
            for (int ks = 0; ks < 4; ++ks) {
                uint4 bv = *(const uint4*)&WbH[(size_t)((((ks << 3) | ct) << 6) | lane) << 2];
                __builtin_memcpy(&bfrag[ks], &bv, 16);
            }
            f32x4 acc = {0.f, 0.f, 0.f, 0.f};
#pragma unroll
            for (int ks = 0; ks < 4; ++ks) {
                f16x8 af;
                uint4 av = *(const uint4*)&wr[w4].p.h1[l15 * 68 + (((ks << 2) + quad) << 2)];
                __builtin_memcpy(&af, &av, 16);
                acc = __builtin_amdgcn_mfma_f32_16x16x32_f16(af, bfrag[ks], acc, 0, 0, 0);
            }
            float bb = Bb[(ct << 4) + l15];
#pragma unroll
            for (int r = 0; r < 4; ++r) {
                float v = fmaxf(acc[r] + bb, 0.f);
                float vp = __shfl_xor(v, 1, 64);
                if (!(l15 & 1)) {
                    int rowi = (quad << 2) + r;       // chunk row 0..15
                    int d = (ct << 3) + (l15 >> 1);
                    int chn = d >> 2, din = d & 3;
                    wr[w4].p.h2[(rowi << 6) + ((chn ^ rowi) << 2) + din] = packh2(v, vp);
                }
            }
        }
        // --- L3 partial: acc C[16 rows x 256 cols], fold masked max ---
#pragma unroll
        for (int ct = 0; ct < 16; ++ct) {
            f16x8 cf[4];
#pragma unroll
            for (int ks = 0; ks < 4; ++ks) {
                uint4 bv = *(const uint4*)&WcH[(size_t)((((ks << 4) | ct) << 6) | lane) << 2];
                __builtin_memcpy(&cf[ks], &bv, 16);
            }
            f32x4 acc = {0.f, 0.f, 0.f, 0.f};
#pragma unroll
            for (int ks = 0; ks < 4; ++ks) {
                f16x8 af;
                uint4 av = *(const uint4*)&wr[w4].p.h2[(l15 << 6) +
                                                       ((((ks << 2) | quad) ^ l15) << 2)];
                __builtin_memcpy(&af, &av, 16);
                acc = __builtin_amdgcn_mfma_f32_16x16x32_f16(af, cf[ks], acc, 0, 0, 0);
            }
            int nb0 = (rt << 4) + (quad << 2);        // global neighbor row base
#pragma unroll
            for (int r = 0; r < 4; ++r) {
                float v = (nb0 + r < nb) ? acc[r] : -1e30f;
                runM[ct][r] = fmaxf(runM[ct][r], v);
            }
        }
    }
    // --- epilogue: cross-quad fold and write ---
#pragma unroll
    for (int ct = 0; ct < 16; ++ct) {
        float m = fmaxf(fmaxf(runM[ct][0], runM[ct][1]),
                        fmaxf(runM[ct][2], runM[ct][3]));
        m = fmaxf(m, __shfl_xor(m, 16, 64));
        m = fmaxf(m, __shfl_xor(m, 32, 64));
        if (lane < 16) {
            int col = (ct << 4) + l15;
            Aout[(size_t)g * 260 + col] = m + Bc[col];
        }
    }
}

// ---------------------------------------------------------------------------
// Barrier-free MFMA GEMM with pre-packed fp16 B: C[M,N] = A[M,K] @ B[K,N].
// One wave owns a 16-row x 128-col C strip. If gmax != null: fused per-cloud
// col max via encoded atomicMax (cloud = row/256).
// ---------------------------------------------------------------------------
__global__ __launch_bounds__(256) void gemm_mfma2(
    const float* __restrict__ A, int lda, const unsigned* __restrict__ Bp, int nct,
    const float* __restrict__ bias, float* __restrict__ C, int ldc, int K,
    int relu, unsigned* __restrict__ gmax) {
    int w = (blockIdx.x << 2) + (TID >> 6);
    int ncg = nct >> 3;
    int rs = w / ncg, cg = w - rs * ncg;
    int r0 = rs << 4, ct0 = cg << 3;
    int lane = TID & 63, quad = lane >> 4, l15 = lane & 15;
    f32x4 acc[8];
#pragma unroll
    for (int ct = 0; ct < 8; ++ct) acc[ct] = (f32x4){0.f, 0.f, 0.f, 0.f};
    const float* ar = A + (size_t)(r0 + l15) * lda;
    int nks = (K + 31) >> 5;
    for (int ks = 0; ks < nks; ++ks) {
        int kb = (ks << 5) + (quad << 3);
        f16x8 af;
        if (kb + 8 <= K) {
            float4 a0 = *(const float4*)(ar + kb);
            float4 a1 = *(const float4*)(ar + kb + 4);
            uint4 av = make_uint4(packh2(a0.x, a0.y), packh2(a0.z, a0.w),
                                  packh2(a1.x, a1.y), packh2(a1.z, a1.w));
            __builtin_memcpy(&af, &av, 16);
        } else {
            float f[8];
#pragma unroll
            for (int j = 0; j < 8; ++j) f[j] = (kb + j < K) ? ar[kb + j] : 0.f;
            uint4 av = make_uint4(packh2(f[0], f[1]), packh2(f[2], f[3]),
                                  packh2(f[4], f[5]), packh2(f[6], f[7]));
            __builtin_memcpy(&af, &av, 16);
        }
#pragma unroll
        for (int ct = 0; ct < 8; ++ct) {
            uint4 bv = *(const uint4*)&Bp[(size_t)(((ks * nct + ct0 + ct) << 6) | lane) << 2];
            f16x8 bf;
            __builtin_memcpy(&bf, &bv, 16);
            acc[ct] = __builtin_amdgcn_mfma_f32_16x16x32_f16(af, bf, acc[ct], 0, 0, 0);
        }
    }
    if (!gmax) {
#pragma unroll
        for (int ct = 0; ct < 8; ++ct) {
            int col = ((ct0 + ct) << 4) + l15;
            float bb = bias[col];
#pragma unroll
            for (int r = 0; r < 4; ++r) {
                int row = r0 + (quad << 2) + r;   // C row = quad*4 + r
                float v = acc[ct][r] + bb;
                if (relu) v = fmaxf(v, 0.f);
                C[(size_t)row * ldc + col] = v;
            }
        }
    } else {
        int cloud = r0 >> 8;
#pragma unroll
        for (int ct = 0; ct < 8; ++ct) {
            int col = ((ct0 + ct) << 4) + l15;
            float bb = bias[col];
            float m = fmaxf(fmaxf(acc[ct][0], acc[ct][1]),
                            fmaxf(acc[ct][2], acc[ct][3])) + bb;
            m = fmaxf(m, __shfl_xor(m, 16, 64));
            m = fmaxf(m, __shfl_xor(m, 32, 64));
            if (quad == 0) atomicMax(&gmax[(cloud << 10) + col], encf(m));
        }
    }
}

// ---------------------------------------------------------------------------
// Head MLP 1024->512->256->10 + log_softmax (one block per cloud).
// ---------------------------------------------------------------------------
__global__ __launch_bounds__(256) void head_kernel(
    const unsigned* __restrict__ gfeatE,
    const float* __restrict__ Wh1, const float* __restrict__ bh1,
    const float* __restrict__ Wh2, const float* __restrict__ bh2,
    const float* __restrict__ Wh3, const float* __restrict__ bh3,
    float* __restrict__ out) {
    __shared__ float gg[1024];
    __shared__ float s1[512];
    __shared__ float s2[256];
    __shared__ float lg[10];
    int cloud = blockIdx.x;
    for (int i = TID; i < 1024; i += 256) gg[i] = decf(gfeatE[(cloud << 10) + i]);
    __syncthreads();
    for (int cc = TID; cc < 512; cc += 256) {
        float v = bh1[cc];
        for (int i = 0; i < 1024; ++i) v = fmaf(gg[i], Wh1[i * 512 + cc], v);
        s1[cc] = fmaxf(v, 0.f);
    }
    __syncthreads();
    for (int cc = TID; cc < 256; cc += 256) {
        float v = bh2[cc];
        for (int i = 0; i < 512; ++i) v = fmaf(s1[i], Wh2[i * 256 + cc], v);
        s2[cc] = fmaxf(v, 0.f);
    }
    __syncthreads();
    if (TID < 10) {
        float v = bh3[TID];
        for (int i = 0; i < 256; ++i) v = fmaf(s2[i], Wh3[i * 10 + TID], v);
        lg[TID] = v;
    }
    __syncthreads();
    if (TID == 0) {
        float mx = lg[0];
        for (int i = 1; i < 10; ++i) mx = fmaxf(mx, lg[i]);
        float s = 0.f;
        for (int i = 0; i < 10; ++i) s += expf(lg[i] - mx);
        float lse = mx + logf(s);
        for (int i = 0; i < 10; ++i) out[cloud * 10 + i] = lg[i] - lse;
    }
}

// ---------------------------------------------------------------------------
// Launch. Workspace layout (peak 10.4 MB).
// Packed fp16 weights: WcH@335872(64K) WaH@401408(40K) WbH@442368(32K)
//                      W3aH@8945664(144K) W3bH@9093120(256K) W3cH@9355264(1M).
// ---------------------------------------------------------------------------
extern "C" void kernel_launch(void* const* d_in, const int* in_sizes, int n_in,
                              void* d_out, int out_size, void* d_ws, size_t ws_size,
                              hipStream_t stream) {
    (void)in_sizes; (void)n_in; (void)out_size; (void)ws_size;
    const float* pos = (const float*)d_in[0];
    const float* W1a = (const float*)d_in[1];  const float* b1a = (const float*)d_in[2];
    const float* W1b = (const float*)d_in[3];  const float* b1b = (const float*)d_in[4];
    const float* W1c = (const float*)d_in[5];  const float* b1c = (const float*)d_in[6];
    const float* W2a = (const float*)d_in[7];  const float* b2a = (const float*)d_in[8];
    const float* W2b = (const float*)d_in[9];  const float* b2b = (const float*)d_in[10];
    const float* W2c = (const float*)d_in[11]; const float* b2c = (const float*)d_in[12];
    const float* W3a = (const float*)d_in[13]; const float* b3a = (const float*)d_in[14];
    const float* W3b = (const float*)d_in[15]; const float* b3b = (const float*)d_in[16];
    const float* W3c = (const float*)d_in[17]; const float* b3c = (const float*)d_in[18];
    const float* Wh1 = (const float*)d_in[19]; const float* bh1 = (const float*)d_in[20];
    const float* Wh2 = (const float*)d_in[21]; const float* bh2 = (const float*)d_in[22];
    const float* Wh3 = (const float*)d_in[23]; const float* bh3 = (const float*)d_in[24];

    char* ws = (char*)d_ws;
    float*    curv   = (float*)(ws + 0);
    float4*   pos1   = (float4*)(ws + 98304);
    float*    curv1  = (float*)(ws + 229376);
    float4*   pos2   = (float4*)(ws + 270336);
    unsigned* gfeatE = (unsigned*)(ws + 303104);
    unsigned* WcH    = (unsigned*)(ws + 335872);
    unsigned* WaH    = (unsigned*)(ws + 401408);
    unsigned* WbH    = (unsigned*)(ws + 442368);
    float*    x1     = (float*)(ws + 524288);
    float*    Abuf   = (float*)(ws + 4718592);
    float*    h1g    = (float*)(ws + 6848512);
    unsigned* W3aH   = (unsigned*)(ws + 8945664);
    unsigned* W3bH   = (unsigned*)(ws + 9093120);
    unsigned* W3cH   = (unsigned*)(ws + 9355264);
    float*    h2g    = x1;    // x1 dead after conv2

    pack_curv_kernel<<<454, 256, 0, stream>>>(W2c, W2a, W2b, W3a, W3b, W3c,
                                              WcH, WaH, WbH, W3aH, W3bH, W3cH,
                                              gfeatE, pos, curv);
    fps1_kernel<<<8, 256, 0, stream>>>(pos, curv, pos1, curv1);
    fps2_conv1_kernel<<<2056, 256, 0, stream>>>(pos, pos1, curv1, pos2, Abuf,
                                                W1a, b1a, W1b, b1b, W1c, b1c, x1);
    conv2_kernel<<<512, 256, 0, stream>>>(pos1, pos2, x1, WaH, b2a, WbH, b2b, WcH, b2c,
                                          Abuf);
    gemm_mfma2<<<64, 256, 0, stream>>>(Abuf, 260, W3aH, 16, b3a, h1g, 256,
                                       259, 1, nullptr);
    gemm_mfma2<<<128, 256, 0, stream>>>(h1g, 256, W3bH, 32, b3b, h2g, 512,
                                        256, 1, nullptr);
    gemm_mfma2<<<256, 256, 0, stream>>>(h2g, 512, W3cH, 64, b3c, nullptr, 0,
                                        512, 0, gfeatE);
    head_kernel<<<8, 256, 0, stream>>>(gfeatE, Wh1, bh1, Wh2, bh2, Wh3, bh3,
                                       (float*)d_out);
}

// Round 13
// 1319.201 us; speedup vs baseline: 1.0346x; 1.0346x over previous
//
#include <hip/hip_runtime.h>
#include <hip/hip_fp16.h>
#include <math.h>

#define TID threadIdx.x

typedef _Float16 h2vec __attribute__((ext_vector_type(2)));
typedef _Float16 f16x8 __attribute__((ext_vector_type(8)));
typedef float f32x4 __attribute__((ext_vector_type(4)));
typedef float f32x2v __attribute__((ext_vector_type(2)));

#if __has_builtin(__builtin_elementwise_fma)
#define EFMA(a, b, c) __builtin_elementwise_fma((a), (b), (c))
#else
static __device__ __forceinline__ f32x2v EFMA(f32x2v a, f32x2v b, f32x2v c) {
    f32x2v r;
    r.x = fmaf(a.x, b.x, c.x);
    r.y = fmaf(a.y, b.y, c.y);
    return r;
}
#endif

// fp16 pair dot into fp32 accumulator: v_dot2_f32_f16
static __device__ __forceinline__ float fdot2(unsigned a, unsigned b, float c) {
    h2vec av, bv;
    __builtin_memcpy(&av, &a, 4);
    __builtin_memcpy(&bv, &b, 4);
    return __builtin_amdgcn_fdot2(av, bv, c, false);
}

static __device__ __forceinline__ unsigned packh2(float a, float b) {
    __half2 hh = __floats2half2_rn(a, b);
    unsigned u;
    __builtin_memcpy(&u, &hh, 4);
    return u;
}

// Monotone float<->uint encoding for integer atomicMax on floats.
static __device__ __forceinline__ unsigned encf(float f) {
    unsigned u = __float_as_uint(f);
    return (u >> 31) ? ~u : (u | 0x80000000u);
}
static __device__ __forceinline__ float decf(unsigned e) {
    unsigned u = (e >> 31) ? (e & 0x7fffffffu) : ~e;
    return __uint_as_float(u);
}

// Wave-uniform sum via DPP ladder; only lane63 true total, readlane broadcasts.
static __device__ __forceinline__ int wave_sum(int v) {
    v += __builtin_amdgcn_update_dpp(0, v, 0x111, 0xf, 0xf, true);  // row_shr:1
    v += __builtin_amdgcn_update_dpp(0, v, 0x112, 0xf, 0xf, true);  // row_shr:2
    v += __builtin_amdgcn_update_dpp(0, v, 0x114, 0xf, 0xf, true);  // row_shr:4
    v += __builtin_amdgcn_update_dpp(0, v, 0x118, 0xf, 0xf, true);  // row_shr:8
    v += __builtin_amdgcn_update_dpp(0, v, 0x142, 0xf, 0xf, true);  // row_bcast15
    v += __builtin_amdgcn_update_dpp(0, v, 0x143, 0xf, 0xf, true);  // row_bcast31
    return __builtin_amdgcn_readlane(v, 63);
}

// u64 max with partner brought in by DPP; bound_ctrl=true shifts in 0 (identity).
template <int CTRL>
static __device__ __forceinline__ unsigned long long dpp_max_u64(unsigned long long k) {
    int lo = (int)(unsigned)(k & 0xffffffffULL);
    int hi = (int)(unsigned)(k >> 32);
    int lo2 = __builtin_amdgcn_update_dpp(0, lo, CTRL, 0xf, 0xf, true);
    int hi2 = __builtin_amdgcn_update_dpp(0, hi, CTRL, 0xf, 0xf, true);
    unsigned long long k2 = ((unsigned long long)(unsigned)hi2 << 32) | (unsigned)lo2;
    return k2 > k ? k2 : k;
}

// ---------------------------------------------------------------------------
// fp32 -> fp16 B-fragment pack for mfma_f32_16x16x32_f16 (one slot per t).
// ---------------------------------------------------------------------------
static __device__ __forceinline__ void pack_slot(const float* __restrict__ W,
                                                 unsigned* __restrict__ out,
                                                 int K, int ncols, int t) {
    int lane = t & 63;
    int frag = t >> 6;
    int nct = ncols >> 4;
    int ks = frag / nct, ct = frag - ks * nct;
    int kbase = (ks << 5) + ((lane >> 4) << 3);
    int cc = (ct << 4) + (lane & 15);
    unsigned o[4];
#pragma unroll
    for (int i = 0; i < 4; ++i) {
        int k0 = kbase + 2 * i, k1 = kbase + 2 * i + 1;
        float f0 = (k0 < K) ? W[(size_t)k0 * ncols + cc] : 0.f;
        float f1 = (k1 < K) ? W[(size_t)k1 * ncols + cc] : 0.f;
        o[i] = packh2(f0, f1);
    }
    *(uint4*)&out[(size_t)t * 4] = make_uint4(o[0], o[1], o[2], o[3]);
}

// ---------------------------------------------------------------------------
// Curvature: per-point 10-NN covariance, lambda_min / sum(lambda)
// ---------------------------------------------------------------------------
__global__ __launch_bounds__(256) void curv_kernel(const float* __restrict__ pos,
                                                   float* __restrict__ curv) {
    __shared__ float4 sp[2048];
    int cloud = blockIdx.x >> 3;
    int base = cloud << 11;
    for (int j = TID; j < 2048; j += 256) {
        const float* p = pos + (size_t)(base + j) * 3;
        float x = p[0], y = p[1], z = p[2];
        sp[j] = make_float4(x, y, z, fmaf(x, x, fmaf(y, y, z * z)));
    }
    __syncthreads();
    int li = ((blockIdx.x & 7) << 8) + TID;
    float4 pi = sp[li];
    float bd[10];
    int bi[10];
#pragma unroll
    for (int t = 0; t < 10; ++t) { bd[t] = 3.0e38f; bi[t] = 0; }
    for (int j = 0; j < 2048; ++j) {
        float4 pj = sp[j];
        float dot = fmaf(pi.x, pj.x, fmaf(pi.y, pj.y, pi.z * pj.z));
        float d2 = pi.w + pj.w - 2.0f * dot;   // same form as reference _sqdist
        if (d2 < bd[9]) {
            bd[9] = d2; bi[9] = j;
#pragma unroll
            for (int t = 9; t > 0; --t) {
                if (bd[t] < bd[t - 1]) {
                    float td = bd[t]; bd[t] = bd[t - 1]; bd[t - 1] = td;
                    int ti = bi[t]; bi[t] = bi[t - 1]; bi[t - 1] = ti;
                }
            }
        }
    }
    double sx = 0, sy = 0, sz = 0;
#pragma unroll
    for (int t = 0; t < 10; ++t) { float4 p = sp[bi[t]]; sx += p.x; sy += p.y; sz += p.z; }
    double mx = sx / 10.0, my = sy / 10.0, mz = sz / 10.0;
    double cxx = 0, cxy = 0, cxz = 0, cyy = 0, cyz = 0, czz = 0;
#pragma unroll
    for (int t = 0; t < 10; ++t) {
        float4 p = sp[bi[t]];
        double dx = p.x - mx, dy = p.y - my, dz = p.z - mz;
        cxx += dx * dx; cxy += dx * dy; cxz += dx * dz;
        cyy += dy * dy; cyz += dy * dz; czz += dz * dz;
    }
    cxx /= 10.0; cxy /= 10.0; cxz /= 10.0; cyy /= 10.0; cyz /= 10.0; czz /= 10.0;
    double q = (cxx + cyy + czz) / 3.0;
    double b00 = cxx - q, b11 = cyy - q, b22 = czz - q;
    double p2 = b00 * b00 + b11 * b11 + b22 * b22 +
                2.0 * (cxy * cxy + cxz * cxz + cyz * cyz);
    double lmin;
    if (p2 <= 0.0) {
        lmin = q;
    } else {
        double p = sqrt(p2 / 6.0);
        double inv = 1.0 / p;
        double c00 = b00 * inv, c01 = cxy * inv, c02 = cxz * inv;
        double c11 = b11 * inv, c12 = cyz * inv, c22 = b22 * inv;
        double detB = c00 * (c11 * c22 - c12 * c12)
                    - c01 * (c01 * c22 - c12 * c02)
                    + c02 * (c01 * c12 - c11 * c02);
        double r = 0.5 * detB;
        r = fmin(1.0, fmax(-1.0, r));
        double phi = acos(r) / 3.0;
        lmin = q + 2.0 * p * cos(phi + 2.0943951023931953);  // smallest eigenvalue
    }
    double s3 = cxx + cyy + czz;
    curv[base + li] = (float)(lmin / (s3 + 1e-8));
}

// ---------------------------------------------------------------------------
// Weighted FPS body — round-9 proven structure (measured best): 4 waves,
// packed f32x2 update, u64 key tree per lane, u64 DPP max ladder, lane63
// posts 1 record/wave, single barrier, fold 4. Key=(score_bits<<32)|(2047-idx).
// ---------------------------------------------------------------------------
template <int N, int M, int SLOTS>
static __device__ void fps_body(
    const float* __restrict__ srcpos, int stride, const float* __restrict__ srccurv,
    int cloud, float4* __restrict__ outPos, float* __restrict__ outCurv,
    float* __restrict__ outA, int ldA,
    float4* sp, int* sidx, unsigned long long* rec /* [8] */) {
    constexpr int PAIRS = SLOTS / 2;
    const float* cp = srcpos + (size_t)cloud * N * stride;
    for (int j = TID; j < N; j += 256)
        sp[j] = make_float4(cp[j * stride], cp[j * stride + 1], cp[j * stride + 2], 0.f);
    if (TID == 0) sidx[0] = 0;
    __syncthreads();
    f32x2v px[PAIRS], py[PAIRS], pz[PAIRS], md[PAIRS], wvv[PAIRS];
#pragma unroll
    for (int s = 0; s < PAIRS; ++s) {
        int p0 = ((2 * s) << 8) + TID, p1 = ((2 * s + 1) << 8) + TID;
        float4 q0 = sp[p0], q1 = sp[p1];
        px[s].x = q0.x; px[s].y = q1.x;
        py[s].x = q0.y; py[s].y = q1.y;
        pz[s].x = q0.z; pz[s].y = q1.z;
        md[s].x = 3.0e38f; md[s].y = 3.0e38f;
        wvv[s].x = fmaf(10.0f, srccurv[cloud * N + p0], 1.0f);
        wvv[s].y = fmaf(10.0f, srccurv[cloud * N + p1], 1.0f);
    }
    int lane = TID & 63, w4 = TID >> 6;
    float4 c0 = sp[0];
    float cx = c0.x, cy = c0.y, cz = c0.z;
    for (int t = 1; t < M; ++t) {
        f32x2v cxv, cyv, czv;
        cxv.x = cx; cxv.y = cx; cyv.x = cy; cyv.y = cy; czv.x = cz; czv.y = cz;
        unsigned long long kk[PAIRS];
#pragma unroll
        for (int s = 0; s < PAIRS; ++s) {
            f32x2v dx = px[s] - cxv, dy = py[s] - cyv, dz = pz[s] - czv;
            f32x2v nd = EFMA(dx, dx, EFMA(dy, dy, dz * dz));
            f32x2v m2 = __builtin_elementwise_min(md[s], nd);
            md[s] = m2;
            f32x2v sc = m2 * wvv[s];
            // score >= 0 -> float bits monotone under unsigned compare
            unsigned long long k0 =
                ((unsigned long long)__float_as_uint(sc.x) << 32) |
                (unsigned)(2047 - (((2 * s) << 8) + TID));
            unsigned long long k1 =
                ((unsigned long long)__float_as_uint(sc.y) << 32) |
                (unsigned)(2047 - (((2 * s + 1) << 8) + TID));
            kk[s] = k0 > k1 ? k0 : k1;
        }
        unsigned long long k = kk[0];
#pragma unroll
        for (int s = 1; s < PAIRS; ++s) k = kk[s] > k ? kk[s] : k;
        k = dpp_max_u64<0x111>(k);   // row_shr:1
        k = dpp_max_u64<0x112>(k);   // row_shr:2
        k = dpp_max_u64<0x114>(k);   // row_shr:4
        k = dpp_max_u64<0x118>(k);   // row_shr:8
        k = dpp_max_u64<0x142>(k);   // row_bcast15
        k = dpp_max_u64<0x143>(k);   // row_bcast31 -> lane63 has wave max
        int pbase = (t & 1) << 2;
        if (lane == 63) rec[pbase | w4] = k;
        __syncthreads();
        unsigned long long k0 = rec[pbase + 0];
        unsigned long long k1 = rec[pbase + 1];
        unsigned long long k2 = rec[pbase + 2];
        unsigned long long k3 = rec[pbase + 3];
        unsigned long long ka = k0 > k1 ? k0 : k1;
        unsigned long long kb = k2 > k3 ? k2 : k3;
        unsigned long long km = ka > kb ? ka : kb;
        int nbix = 2047 - (int)(unsigned)(km & 0xffffffffULL);  // uniform winner
        if (TID == 0) sidx[t] = nbix;
        float4 cc = sp[nbix];        // uniform (broadcast) read
        cx = cc.x; cy = cc.y; cz = cc.z;
    }
    __syncthreads();
    for (int j = TID; j < M; j += 256) {
        int id = sidx[j];
        float4 qv = sp[id];
        outPos[cloud * M + j] = qv;
        if (outCurv) outCurv[cloud * M + j] = srccurv[cloud * N + id];
        if (outA) {
            float* a = outA + (size_t)(cloud * M + j) * ldA;
            a[256] = qv.x; a[257] = qv.y; a[258] = qv.z;
        }
    }
}

// ---------------------------------------------------------------------------
// fps1 + weight packing in one launch. Blocks 0-7: fps1 (serial, 8 CUs for
// ~440 us). Blocks 8-397: fragment-pack the 6 weight matrices (independent
// of fps1; hidden entirely under its shadow). Block 8 inits gfeat encodings.
// ---------------------------------------------------------------------------
__global__ __launch_bounds__(256, 1) void fps1_pack_kernel(
    const float* __restrict__ pos, const float* __restrict__ curv,
    float4* __restrict__ pos1, float* __restrict__ curv1,
    const float* __restrict__ Wc, const float* __restrict__ Wa,
    const float* __restrict__ Wb, const float* __restrict__ W3a,
    const float* __restrict__ W3b, const float* __restrict__ W3c,
    unsigned* __restrict__ WcH, unsigned* __restrict__ WaH,
    unsigned* __restrict__ WbH, unsigned* __restrict__ W3aH,
    unsigned* __restrict__ W3bH, unsigned* __restrict__ W3cH,
    unsigned* __restrict__ gfeatE) {
    __shared__ float4 sp[2048];
    __shared__ int sidx[1024];
    __shared__ unsigned long long rec[8];
    if (blockIdx.x < 8) {
        fps_body<2048, 1024, 8>(pos, 3, curv, blockIdx.x, pos1, curv1, nullptr, 0,
                                sp, sidx, rec);
        return;
    }
    int b = blockIdx.x - 8;
    if (b == 0)
        for (int i = TID; i < 8192; i += 256) gfeatE[i] = 0u;  // enc identity
    if (b < 16)        pack_slot(Wc,  WcH,  128, 256,  b * 256 + TID);
    else if (b < 26)   pack_slot(Wa,  WaH,  131, 128,  (b - 16) * 256 + TID);
    else if (b < 34)   pack_slot(Wb,  WbH,  128, 128,  (b - 26) * 256 + TID);
    else if (b < 70)   pack_slot(W3a, W3aH, 259, 256,  (b - 34) * 256 + TID);
    else if (b < 134)  pack_slot(W3b, W3bH, 256, 512,  (b - 70) * 256 + TID);
    else               pack_slot(W3c, W3cH, 512, 1024, (b - 134) * 256 + TID);
}

// ---------------------------------------------------------------------------
// Exact top-64 (smallest d2, idx tie-break) selection within one wave.
// ---------------------------------------------------------------------------
static __device__ __forceinline__ int select_k64(const unsigned int* ck, const int* ci,
                                                 int c, int lane, int* cnt2, int* sel,
                                                 int* nbOut) {
    if (c <= 64) {
        *nbOut = c;
        return (lane < c) ? ci[lane] : 0;
    }
    unsigned int T = 0;  // becomes the 64th-smallest key
    for (int bit = 31; bit >= 0; --bit) {
        unsigned int mid = T | (1u << bit);
        int cl = 0;
        for (int q = lane; q < c; q += 64) cl += (ck[q] < mid) ? 1 : 0;
        if (wave_sum(cl) < 64) T = mid;
    }
    int cl = 0;
    for (int q = lane; q < c; q += 64) cl += (ck[q] < T) ? 1 : 0;
    int need = 64 - wave_sum(cl);
    int TI = 0;  // becomes the need-th smallest idx among keys == T
    for (int bit = 11; bit >= 0; --bit) {
        int mid = TI | (1 << bit);
        int ce = 0;
        for (int q = lane; q < c; q += 64) ce += (ck[q] == T && ci[q] < mid) ? 1 : 0;
        if (wave_sum(ce) < need) TI = mid;
    }
    for (int q = lane; q < c; q += 64) {
        unsigned int kq = ck[q];
        int iq = ci[q];
        if (kq < T || (kq == T && iq <= TI)) sel[atomicAdd(cnt2, 1)] = iq;
    }
    *nbOut = 64;
    return sel[lane];
}

// ---------------------------------------------------------------------------
// SA1 conv body (3->64->64->128). h2 staged to LDS as fp16 pairs; L3 is
// weights-stationary: lane = channel (wave-pair covers 128 ch), fdot2 inner.
// ---------------------------------------------------------------------------
union U1 {
    struct {
        float4 sp[2048];
        unsigned ck[4][256];
        int ci[4][256];
        int sel[4][64];
        int cnt[4], cnt2[4];
    } p;
    unsigned h2s[4][2048];   // [cent][n*32 + ((q*4) ^ ((n&7)*4)) + k], half2 elems
};

static __device__ void conv1_body(
    int bid, U1& u,
    const float* __restrict__ pos, const float4* __restrict__ pos1,
    const float* __restrict__ W1, const float* __restrict__ B1,
    const float* __restrict__ W2, const float* __restrict__ B2,
    const float* __restrict__ W3, const float* __restrict__ B3,
    float* __restrict__ x1) {
    __shared__ int nbs[4];
    int cloud = bid >> 8;
    int w4 = TID >> 6, lane = TID & 63;
    int centb = (bid & 255) << 2;
    int g = (cloud << 10) + centb + w4;
    int base = cloud << 11;
    for (int j = TID; j < 2048; j += 256) {
        const float* p = pos + (size_t)(base + j) * 3;
        u.p.sp[j] = make_float4(p[0], p[1], p[2], 0.f);
    }
    if (lane == 0) { u.p.cnt[w4] = 0; u.p.cnt2[w4] = 0; }
    __syncthreads();
    float4 cq = pos1[g];
    double cx = cq.x, cy = cq.y, cz = cq.z;
    for (int s = 0; s < 32; ++s) {
        int j = (s << 6) + lane;
        float4 pj = u.p.sp[j];
        double dx = (double)pj.x - cx, dy = (double)pj.y - cy, dz = (double)pj.z - cz;
        double d2 = dx * dx + dy * dy + dz * dz;
        if (d2 <= 0.2 * 0.2) {
            int p = atomicAdd(&u.p.cnt[w4], 1);
            if (p < 256) { u.p.ck[w4][p] = __float_as_uint((float)d2); u.p.ci[w4][p] = j; }
        }
    }
    __syncthreads();
    int c = min(u.p.cnt[w4], 256);
    int nb;
    int idxn = select_k64(u.p.ck[w4], u.p.ci[w4], c, lane, &u.p.cnt2[w4],
                          u.p.sel[w4], &nb);
    if (lane == 0) nbs[w4] = nb;
    float4 pn = u.p.sp[idxn];
    float rx = pn.x - cq.x, ry = pn.y - cq.y, rz = pn.z - cq.z;
    float h1[64];
#pragma unroll
    for (int cc2 = 0; cc2 < 64; ++cc2) {
        float v = fmaf(rx, W1[cc2], fmaf(ry, W1[64 + cc2], fmaf(rz, W1[128 + cc2], B1[cc2])));
        h1[cc2] = fmaxf(v, 0.f);
    }
    float h2[64];
#pragma unroll
    for (int cc2 = 0; cc2 < 64; ++cc2) h2[cc2] = B2[cc2];
#pragma unroll
    for (int i = 0; i < 64; ++i) {
        float hv = h1[i];
        const float* wr = W2 + i * 64;
#pragma unroll
        for (int cc2 = 0; cc2 < 64; ++cc2) h2[cc2] = fmaf(hv, wr[cc2], h2[cc2]);
    }
#pragma unroll
    for (int cc2 = 0; cc2 < 64; ++cc2) h2[cc2] = fmaxf(h2[cc2], 0.f);
    __syncthreads();   // all waves done with grouping buffers / sp
    {
        unsigned* hrow = &u.h2s[w4][lane << 5];
        int sw = (lane & 7) << 2;
#pragma unroll
        for (int q = 0; q < 8; ++q) {
            unsigned tmp[4];
#pragma unroll
            for (int k2 = 0; k2 < 4; ++k2) {
                int j = (q << 2) + k2;
                tmp[k2] = packh2(h2[2 * j], h2[2 * j + 1]);
            }
            *(uint4*)&hrow[(q << 2) ^ sw] = make_uint4(tmp[0], tmp[1], tmp[2], tmp[3]);
        }
    }
    __syncthreads();   // h2s + nbs visible block-wide
    // L3: lane = channel (wave pairs cover 128 ch), 2 centroids per lane
    int ch = ((w4 & 1) << 6) + lane;
    int cbase = (w4 >> 1) << 1;
    unsigned w2[32];
#pragma unroll
    for (int p = 0; p < 32; ++p)
        w2[p] = packh2(W3[(2 * p) * 128 + ch], W3[(2 * p + 1) * 128 + ch]);
    float bv = B3[ch];
#pragma unroll 1
    for (int ci2 = 0; ci2 < 2; ++ci2) {
        int cc = cbase + ci2;
        int nbc = nbs[cc];
        float m = -1e30f;
        for (int n = 0; n < nbc; ++n) {
            const unsigned* hr = &u.h2s[cc][n << 5];
            int sw2 = (n & 7) << 2;
            float a0 = 0.f, a1 = 0.f, a2 = 0.f, a3 = 0.f;
#pragma unroll
            for (int q = 0; q < 8; ++q) {
                uint4 hv = *(const uint4*)&hr[(q << 2) ^ sw2];
                a0 = fdot2(hv.x, w2[(q << 2) + 0], a0);
                a1 = fdot2(hv.y, w2[(q << 2) + 1], a1);
                a2 = fdot2(hv.z, w2[(q << 2) + 2], a2);
                a3 = fdot2(hv.w, w2[(q << 2) + 3], a3);
            }
            m = fmaxf(m, bv + (a0 + a1) + (a2 + a3));
        }
        x1[(size_t)((cloud << 10) + centb + cc) * 128 + ch] = m;
    }
}

// ---------------------------------------------------------------------------
// Merged launch: blocks 0-7 run fps2 (1024->256), blocks 8.. run conv1.
// ---------------------------------------------------------------------------
union UM {
    U1 c;
    struct {
        float4 sp[1024];
        unsigned long long rec[8];
        int sidx[256];
    } f;
};

__global__ __launch_bounds__(256, 2) void fps2_conv1_kernel(
    const float* __restrict__ pos, const float4* __restrict__ pos1,
    const float* __restrict__ curv1, float4* __restrict__ pos2,
    float* __restrict__ Abuf,
    const float* __restrict__ W1, const float* __restrict__ B1,
    const float* __restrict__ W2, const float* __restrict__ B2,
    const float* __restrict__ W3, const float* __restrict__ B3,
    float* __restrict__ x1) {
    __shared__ UM u;
    if (blockIdx.x < 8) {
        fps_body<1024, 256, 4>((const float*)pos1, 4, curv1, blockIdx.x, pos2,
                               nullptr, Abuf, 260, u.f.sp, u.f.sidx, u.f.rec);
    } else {
        conv1_body(blockIdx.x - 8, u.c, pos, pos1, W1, B1, W2, B2, W3, B3, x1);
    }
}

// ---------------------------------------------------------------------------
// SA2: radius r=0.4 grouping + PointNetConv(131->128->128->256), all 3 layers
// as MFMA GEMMs (v_mfma_f32_16x16x32_f16). Round-11 measured-best version.
// ---------------------------------------------------------------------------
union U2 {
    struct {
        float4 sp[1024];
        unsigned ck[4][512];
        int ci[4][512];
        int sel[4][64];
        int cnt[4], cnt2[4];
    } p;
    unsigned xs[4][5376];   // 84 dwords/row x 64 rows; h2s[cent]=xs[cent][0..4095]
};

__global__ __launch_bounds__(256, 1) void conv2_kernel(
    const float4* __restrict__ pos1, const float4* __restrict__ pos2,
    const float* __restrict__ x1,
    const unsigned* __restrict__ WaH, const float* __restrict__ Ba,
    const unsigned* __restrict__ WbH, const float* __restrict__ Bb,
    const unsigned* __restrict__ WcH, const float* __restrict__ Bc,
    float* __restrict__ Aout) {
    __shared__ U2 u;
    __shared__ unsigned h1s[4][4352];   // 68 dwords/row x 64 rows (fp16 pairs)
    __shared__ int nbs[4];
    int cloud = blockIdx.x >> 6;
    int w4 = TID >> 6, lane = TID & 63;
    int centb = (blockIdx.x & 63) << 2;
    int g = (cloud << 8) + centb + w4;
    int quad = lane >> 4, l15 = lane & 15;
    for (int j = TID; j < 1024; j += 256) u.p.sp[j] = pos1[(cloud << 10) + j];
    if (lane == 0) { u.p.cnt[w4] = 0; u.p.cnt2[w4] = 0; }
    __syncthreads();
    float4 cq = pos2[g];
    double cx = cq.x, cy = cq.y, cz = cq.z;
    for (int s = 0; s < 16; ++s) {
        int j = (s << 6) + lane;
        float4 pj = u.p.sp[j];
        double dx = (double)pj.x - cx, dy = (double)pj.y - cy, dz = (double)pj.z - cz;
        double d2 = dx * dx + dy * dy + dz * dz;
        if (d2 <= 0.4 * 0.4) {
            int p = atomicAdd(&u.p.cnt[w4], 1);
            if (p < 512) { u.p.ck[w4][p] = __float_as_uint((float)d2); u.p.ci[w4][p] = j; }
        }
    }
    __syncthreads();
    int c = min(u.p.cnt[w4], 512);
    int nb;
    int idxn = select_k64(u.p.ck[w4], u.p.ci[w4], c, lane, &u.p.cnt2[w4],
                          u.p.sel[w4], &nb);
    if (lane == 0) nbs[w4] = nb;
    float4 pn = u.p.sp[idxn];
    float rx = pn.x - cq.x, ry = pn.y - cq.y, rz = pn.z - cq.z;
    __syncthreads();   // grouping LDS dead -> xs may overwrite
    // --- stage xs: lane = row, gathered x1 row as fp16 + rel + zero pad ---
    {
        const float4* xr = (const float4*)(x1 + (size_t)((cloud << 10) + idxn) * 128);
        unsigned* row = &u.xs[w4][lane * 84];
#pragma unroll
        for (int q = 0; q < 16; ++q) {
            float4 a = xr[q * 2], b = xr[q * 2 + 1];
            *(uint4*)&row[q << 2] = make_uint4(packh2(a.x, a.y), packh2(a.z, a.w),
                                               packh2(b.x, b.y), packh2(b.z, b.w));
        }
        *(uint4*)&row[64] = make_uint4(packh2(rx, ry), packh2(rz, 0.f), 0u, 0u);
        *(uint4*)&row[68] = make_uint4(0u, 0u, 0u, 0u);
        *(uint4*)&row[72] = make_uint4(0u, 0u, 0u, 0u);
        *(uint4*)&row[76] = make_uint4(0u, 0u, 0u, 0u);
    }
    // --- L1 MFMA: h1[64 x 128] = xs[64 x 160] @ WaH; bias+relu; pack to h1s ---
    float ba8[8];
#pragma unroll
    for (int ct = 0; ct < 8; ++ct) ba8[ct] = Ba[(ct << 4) + l15];
#pragma unroll 1
    for (int ct = 0; ct < 8; ++ct) {
        f16x8 bfrag[5];
#pragma unroll
        for (int ks = 0; ks < 5; ++ks) {
            uint4 bv = *(const uint4*)&WaH[(size_t)((((ks << 3) | ct) << 6) | lane) << 2];
            __builtin_memcpy(&bfrag[ks], &bv, 16);
        }
#pragma unroll
        for (int rt = 0; rt < 4; ++rt) {
            f32x4 acc = {0.f, 0.f, 0.f, 0.f};
#pragma unroll
            for (int ks = 0; ks < 5; ++ks) {
                f16x8 af;
                uint4 av = *(const uint4*)&u.xs[w4][((rt << 4) + l15) * 84 +
                                                    (((ks << 2) + quad) << 2)];
                __builtin_memcpy(&af, &av, 16);
                acc = __builtin_amdgcn_mfma_f32_16x16x32_f16(af, bfrag[ks], acc, 0, 0, 0);
            }
#pragma unroll
            for (int r = 0; r < 4; ++r) {
                float v = fmaxf(acc[r] + ba8[ct], 0.f);
                float vp = __shfl_xor(v, 1, 64);
                if (!(l15 & 1)) {
                    int rowi = (rt << 4) + (quad << 2) + r;
                    h1s[w4][rowi * 68 + (ct << 3) + (l15 >> 1)] = packh2(v, vp);
                }
            }
        }
    }
    // --- L2 MFMA: h2[64 x 128] = h1s[64 x 128] @ WbH; bias+relu; pack to h2s ---
    unsigned* h2w = &u.xs[w4][0];   // h2s region aliases own xs (dead)
#pragma unroll
    for (int ct = 0; ct < 8; ++ct) ba8[ct] = Bb[(ct << 4) + l15];
#pragma unroll 1
    for (int ct = 0; ct < 8; ++ct) {
        f16x8 bfrag[4];
#pragma unroll
        for (int ks = 0; ks < 4; ++ks) {
            uint4 bv = *(const uint4*)&WbH[(size_t)((((ks << 3) | ct) << 6) | lane) << 2];
            __builtin_memcpy(&bfrag[ks], &bv, 16);
        }
#pragma unroll
        for (int rt = 0; rt < 4; ++rt) {
            f32x4 acc = {0.f, 0.f, 0.f, 0.f};
#pragma unroll
            for (int ks = 0; ks < 4; ++ks) {
                f16x8 af;
                uint4 av = *(const uint4*)&h1s[w4][((rt << 4) + l15) * 68 +
                                                   (((ks << 2) + quad) << 2)];
                __builtin_memcpy(&af, &av, 16);
                acc = __builtin_amdgcn_mfma_f32_16x16x32_f16(af, bfrag[ks], acc, 0, 0, 0);
            }
#pragma unroll
            for (int r = 0; r < 4; ++r) {
                float v = fmaxf(acc[r] + ba8[ct], 0.f);
                float vp = __shfl_xor(v, 1, 64);
                if (!(l15 & 1)) {
                    int rowi = (rt << 4) + (quad << 2) + r;
                    int d = (ct << 3) + (l15 >> 1);
                    int ch = d >> 2, din = d & 3;
                    h2w[(rowi << 6) + ((ch ^ (rowi & 15)) << 2) + din] = packh2(v, vp);
                }
            }
        }
    }
    __syncthreads();   // all h2s + nbs visible block-wide
    // --- L3 MFMA: wave w4 owns col-tiles [4*w4, 4*w4+4) of 16 ---
    int ctb = w4 << 2;
    f16x8 cfrag[4][4];   // [ct][ks]
#pragma unroll
    for (int ct = 0; ct < 4; ++ct)
#pragma unroll
        for (int ks = 0; ks < 4; ++ks) {
            uint4 bv = *(const uint4*)&WcH[(size_t)((((ks << 4) | (ctb + ct)) << 6) | lane) << 2];
            __builtin_memcpy(&cfrag[ct][ks], &bv, 16);
        }
#pragma unroll 1
    for (int cent = 0; cent < 4; ++cent) {
        const unsigned* h2r = &u.xs[cent][0];
        int nbc = nbs[cent];
        float runM[4][4];
#pragma unroll
        for (int ct = 0; ct < 4; ++ct)
#pragma unroll
            for (int r = 0; r < 4; ++r) runM[ct][r] = -1e30f;
#pragma unroll
        for (int rt = 0; rt < 4; ++rt) {
            int nl = (rt << 4) + l15;          // A row (neighbor) for this lane
            f16x8 afrag[4];
#pragma unroll
            for (int ks = 0; ks < 4; ++ks) {
                int cp = ((ks << 2) | quad) ^ l15;
                uint4 av = *(const uint4*)&h2r[(nl << 6) + (cp << 2)];
                __builtin_memcpy(&afrag[ks], &av, 16);
            }
#pragma unroll
            for (int ct = 0; ct < 4; ++ct) {
                f32x4 acc = {0.f, 0.f, 0.f, 0.f};
#pragma unroll
                for (int ks = 0; ks < 4; ++ks)
                    acc = __builtin_amdgcn_mfma_f32_16x16x32_f16(afrag[ks], cfrag[ct][ks],
                                                                 acc, 0, 0, 0);
                int nb0 = (rt << 4) + (quad << 2);   // C row = quad*4 + r
#pragma unroll
                for (int r = 0; r < 4; ++r) {
                    float v = (nb0 + r < nbc) ? acc[r] : -1e30f;
                    runM[ct][r] = fmaxf(runM[ct][r], v);
                }
            }
        }
#pragma unroll
        for (int ct = 0; ct < 4; ++ct) {
            float m = fmaxf(fmaxf(runM[ct][0], runM[ct][1]),
                            fmaxf(runM[ct][2], runM[ct][3]));
            m = fmaxf(m, __shfl_xor(m, 16, 64));
            m = fmaxf(m, __shfl_xor(m, 32, 64));
            if (lane < 16) {
                int cc = ((ctb + ct) << 4) | l15;   // C col = lane&15
                Aout[(size_t)((cloud << 8) + centb + cent) * 260 + cc] = m + Bc[cc];
            }
        }
    }
}

// ---------------------------------------------------------------------------
// Barrier-free MFMA GEMM with pre-packed fp16 B: C[M,N] = A[M,K] @ B[K,N].
// One wave owns a 16-row x 128-col C strip. If gmax != null: fused per-cloud
// col max via encoded atomicMax (cloud = row/256).
// ---------------------------------------------------------------------------
__global__ __launch_bounds__(256) void gemm_mfma2(
    const float* __restrict__ A, int lda, const unsigned* __restrict__ Bp, int nct,
    const float* __restrict__ bias, float* __restrict__ C, int ldc, int K,
    int relu, unsigned* __restrict__ gmax) {
    int w = (blockIdx.x << 2) + (TID >> 6);
    int ncg = nct >> 3;
    int rs = w / ncg, cg = w - rs * ncg;
    int r0 = rs << 4, ct0 = cg << 3;
    int lane = TID & 63, quad = lane >> 4, l15 = lane & 15;
    f32x4 acc[8];
#pragma unroll
    for (int ct = 0; ct < 8; ++ct) acc[ct] = (f32x4){0.f, 0.f, 0.f, 0.f};
    const float* ar = A + (size_t)(r0 + l15) * lda;
    int nks = (K + 31) >> 5;
    for (int ks = 0; ks < nks; ++ks) {
        int kb = (ks << 5) + (quad << 3);
        f16x8 af;
        if (kb + 8 <= K) {
            float4 a0 = *(const float4*)(ar + kb);
            float4 a1 = *(const float4*)(ar + kb + 4);
            uint4 av = make_uint4(packh2(a0.x, a0.y), packh2(a0.z, a0.w),
                                  packh2(a1.x, a1.y), packh2(a1.z, a1.w));
            __builtin_memcpy(&af, &av, 16);
        } else {
            float f[8];
#pragma unroll
            for (int j = 0; j < 8; ++j) f[j] = (kb + j < K) ? ar[kb + j] : 0.f;
            uint4 av = make_uint4(packh2(f[0], f[1]), packh2(f[2], f[3]),
                                  packh2(f[4], f[5]), packh2(f[6], f[7]));
            __builtin_memcpy(&af, &av, 16);
        }
#pragma unroll
        for (int ct = 0; ct < 8; ++ct) {
            uint4 bv = *(const uint4*)&Bp[(size_t)(((ks * nct + ct0 + ct) << 6) | lane) << 2];
            f16x8 bf;
            __builtin_memcpy(&bf, &bv, 16);
            acc[ct] = __builtin_amdgcn_mfma_f32_16x16x32_f16(af, bf, acc[ct], 0, 0, 0);
        }
    }
    if (!gmax) {
#pragma unroll
        for (int ct = 0; ct < 8; ++ct) {
            int col = ((ct0 + ct) << 4) + l15;
            float bb = bias[col];
#pragma unroll
            for (int r = 0; r < 4; ++r) {
                int row = r0 + (quad << 2) + r;   // C row = quad*4 + r
                float v = acc[ct][r] + bb;
                if (relu) v = fmaxf(v, 0.f);
                C[(size_t)row * ldc + col] = v;
            }
        }
    } else {
        int cloud = r0 >> 8;
#pragma unroll
        for (int ct = 0; ct < 8; ++ct) {
            int col = ((ct0 + ct) << 4) + l15;
            float bb = bias[col];
            float m = fmaxf(fmaxf(acc[ct][0], acc[ct][1]),
                            fmaxf(acc[ct][2], acc[ct][3])) + bb;
            m = fmaxf(m, __shfl_xor(m, 16, 64));
            m = fmaxf(m, __shfl_xor(m, 32, 64));
            if (quad == 0) atomicMax(&gmax[(cloud << 10) + col], encf(m));
        }
    }
}

// ---------------------------------------------------------------------------
// Head MLP 1024->512->256->10 + log_softmax (one block per cloud).
// ---------------------------------------------------------------------------
__global__ __launch_bounds__(256) void head_kernel(
    const unsigned* __restrict__ gfeatE,
    const float* __restrict__ Wh1, const float* __restrict__ bh1,
    const float* __restrict__ Wh2, const float* __restrict__ bh2,
    const float* __restrict__ Wh3, const float* __restrict__ bh3,
    float* __restrict__ out) {
    __shared__ float gg[1024];
    __shared__ float s1[512];
    __shared__ float s2[256];
    __shared__ float lg[10];
    int cloud = blockIdx.x;
    for (int i = TID; i < 1024; i += 256) gg[i] = decf(gfeatE[(cloud << 10) + i]);
    __syncthreads();
    for (int cc = TID; cc < 512; cc += 256) {
        float v = bh1[cc];
        for (int i = 0; i < 1024; ++i) v = fmaf(gg[i], Wh1[i * 512 + cc], v);
        s1[cc] = fmaxf(v, 0.f);
    }
    __syncthreads();
    for (int cc = TID; cc < 256; cc += 256) {
        float v = bh2[cc];
        for (int i = 0; i < 512; ++i) v = fmaf(s1[i], Wh2[i * 256 + cc], v);
        s2[cc] = fmaxf(v, 0.f);
    }
    __syncthreads();
    if (TID < 10) {
        float v = bh3[TID];
        for (int i = 0; i < 256; ++i) v = fmaf(s2[i], Wh3[i * 10 + TID], v);
        lg[TID] = v;
    }
    __syncthreads();
    if (TID == 0) {
        float mx = lg[0];
        for (int i = 1; i < 10; ++i) mx = fmaxf(mx, lg[i]);
        float s = 0.f;
        for (int i = 0; i < 10; ++i) s += expf(lg[i] - mx);
        float lse = mx + logf(s);
        for (int i = 0; i < 10; ++i) out[cloud * 10 + i] = lg[i] - lse;
    }
}

// ---------------------------------------------------------------------------
// Launch. Workspace layout (peak 10.4 MB).
// Packed fp16 weights: WcH@335872(64K) WaH@401408(40K) WbH@442368(32K)
//                      W3aH@8945664(144K) W3bH@9093120(256K) W3cH@9355264(1M).
// ---------------------------------------------------------------------------
extern "C" void kernel_launch(void* const* d_in, const int* in_sizes, int n_in,
                              void* d_out, int out_size, void* d_ws, size_t ws_size,
                              hipStream_t stream) {
    (void)in_sizes; (void)n_in; (void)out_size; (void)ws_size;
    const float* pos = (const float*)d_in[0];
    const float* W1a = (const float*)d_in[1];  const float* b1a = (const float*)d_in[2];
    const float* W1b = (const float*)d_in[3];  const float* b1b = (const float*)d_in[4];
    const float* W1c = (const float*)d_in[5];  const float* b1c = (const float*)d_in[6];
    const float* W2a = (const float*)d_in[7];  const float* b2a = (const float*)d_in[8];
    const float* W2b = (const float*)d_in[9];  const float* b2b = (const float*)d_in[10];
    const float* W2c = (const float*)d_in[11]; const float* b2c = (const float*)d_in[12];
    const float* W3a = (const float*)d_in[13]; const float* b3a = (const float*)d_in[14];
    const float* W3b = (const float*)d_in[15]; const float* b3b = (const float*)d_in[16];
    const float* W3c = (const float*)d_in[17]; const float* b3c = (const float*)d_in[18];
    const float* Wh1 = (const float*)d_in[19]; const float* bh1 = (const float*)d_in[20];
    const float* Wh2 = (const float*)d_in[21]; const float* bh2 = (const float*)d_in[22];
    const float* Wh3 = (const float*)d_in[23]; const float* bh3 = (const float*)d_in[24];

    char* ws = (char*)d_ws;
    float*    curv   = (float*)(ws + 0);
    float4*   pos1   = (float4*)(ws + 98304);
    float*    curv1  = (float*)(ws + 229376);
    float4*   pos2   = (float4*)(ws + 270336);
    unsigned* gfeatE = (unsigned*)(ws + 303104);
    unsigned* WcH    = (unsigned*)(ws + 335872);
    unsigned* WaH    = (unsigned*)(ws + 401408);
    unsigned* WbH    = (unsigned*)(ws + 442368);
    float*    x1     = (float*)(ws + 524288);
    float*    Abuf   = (float*)(ws + 4718592);
    float*    h1g    = (float*)(ws + 6848512);
    unsigned* W3aH   = (unsigned*)(ws + 8945664);
    unsigned* W3bH   = (unsigned*)(ws + 9093120);
    unsigned* W3cH   = (unsigned*)(ws + 9355264);
    float*    h2g    = x1;    // x1 dead after conv2

    curv_kernel<<<64, 256, 0, stream>>>(pos, curv);
    fps1_pack_kernel<<<398, 256, 0, stream>>>(pos, curv, pos1, curv1,
                                              W2c, W2a, W2b, W3a, W3b, W3c,
                                              WcH, WaH, WbH, W3aH, W3bH, W3cH,
                                              gfeatE);
    fps2_conv1_kernel<<<2056, 256, 0, stream>>>(pos, pos1, curv1, pos2, Abuf,
                                                W1a, b1a, W1b, b1b, W1c, b1c, x1);
    conv2_kernel<<<512, 256, 0, stream>>>(pos1, pos2, x1, WaH, b2a, WbH, b2b, WcH, b2c,
                                          Abuf);
    gemm_mfma2<<<64, 256, 0, stream>>>(Abuf, 260, W3aH, 16, b3a, h1g, 256,
                                       259, 1, nullptr);
    gemm_mfma2<<<128, 256, 0, stream>>>(h1g, 256, W3bH, 32, b3b, h2g, 512,
                                        256, 1, nullptr);
    gemm_mfma2<<<256, 256, 0, stream>>>(h2g, 512, W3cH, 64, b3c, nullptr, 0,
                                        512, 0, gfeatE);
    head_kernel<<<8, 256, 0, stream>>>(gfeatE, Wh1, bh1, Wh2, bh2, Wh3, bh3,
                                       (float*)d_out);
}